// Round 1
// baseline (9870.212 us; speedup 1.0000x reference)
//
#include <hip/hip_runtime.h>

#define NSTEPS 200

__device__ __forceinline__ float sigm(float x){ return 1.0f/(1.0f + __expf(-x)); }

// ---------------- conv0: Cin=1, Cout=64, L 8192->2048 ----------------
__global__ __launch_bounds__(256) void conv0_k(const float* __restrict__ x,
    const float* __restrict__ w, const float* __restrict__ bias, float* __restrict__ out){
  int id = blockIdx.x*256 + threadIdx.x;          // 128*64*2048
  int l = id & 2047; int co = (id>>11) & 63; int b = id>>17;
  const float* xr = x + (size_t)b*8192;
  const float* wr = w + co*31;
  float acc = bias[co];
  int p0 = 4*l - 15;
  #pragma unroll
  for(int k=0;k<31;k++){
    int p = p0 + k;
    float xv = (p >= 0 && p < 8192) ? xr[p] : 0.0f;
    acc = fmaf(wr[k], xv, acc);
  }
  out[id] = fmaxf(acc, 0.0f);
}

// ---------------- generic strided conv (direct, LDS staged) ----------------
// thread: lane -> coA=cot*128+lane (and coA+64), wq: l-group (NB==1) or batch (NB>1)
template<int CIN, int LIN, int LOUT, int LTILE, int NB, int COUT>
__global__ __launch_bounds__(256) void convN_k(const float* __restrict__ in,
    const float* __restrict__ w, const float* __restrict__ bias, float* __restrict__ out){
  constexpr int CC = 4;
  constexpr int SPAN = ((4*LTILE + 27 + 3)/4)*4;
  constexpr int NL = 8;
  constexpr int WROW = 129;   // padded co-slots per (cc,j7) plane
  __shared__ __align__(16) float4 wlds[CC*8*WROW];
  __shared__ __align__(16) float xlds[NB][CC][SPAN];

  int bid = blockIdx.x;
  constexpr int NLT = LOUT/LTILE;
  int lt = bid % NLT; bid /= NLT;
  constexpr int NCOT = COUT/128;
  int cot = bid % NCOT; bid /= NCOT;
  int b0 = bid * NB;
  int l0 = lt * LTILE;
  int tid = threadIdx.x;
  int lane = tid & 63;
  int wq = tid >> 6;
  int coA = cot*128 + lane;
  int lin0 = l0*4 - 15;

  float acc[NL][2];
  #pragma unroll
  for(int i=0;i<NL;i++){ acc[i][0]=0.f; acc[i][1]=0.f; }

  for(int c0=0; c0<CIN; c0+=CC){
    // stage weights, packed as float4 over k: wlds[(cc*8+j7)*WROW+co] = w[k=4*j7..+3]
    for(int idx=tid; idx<128*CC*31; idx+=256){
      int co = idx/(CC*31); int r = idx - co*(CC*31); int cc = r/31; int k = r - cc*31;
      float v = w[(size_t)(cot*128+co)*(CIN*31) + (c0+cc)*31 + k];
      ((float*)wlds)[((cc*8 + (k>>2))*WROW + co)*4 + (k&3)] = v;
    }
    for(int idx=tid; idx<128*CC; idx+=256){     // zero k=31 slot
      int co = idx >> 2; int cc = idx & 3;
      ((float*)wlds)[((cc*8+7)*WROW + co)*4 + 3] = 0.f;
    }
    for(int idx=tid; idx<NB*CC*SPAN; idx+=256){
      int nb = idx/(CC*SPAN); int r = idx - nb*(CC*SPAN); int cc = r/SPAN; int p = r - cc*SPAN;
      int lin = lin0 + p;
      float v = 0.f;
      if(lin >= 0 && lin < LIN) v = in[(size_t)(b0+nb)*((size_t)CIN*LIN) + (size_t)(c0+cc)*LIN + lin];
      xlds[nb][cc][p] = v;
    }
    __syncthreads();
    int mynb = (NB==1) ? 0 : wq;
    int lbase = (NB==1) ? wq*NL : 0;
    #pragma unroll
    for(int cc=0; cc<CC; cc++){
      #pragma unroll
      for(int j7=0;j7<8;j7++){
        float4 wa = wlds[(cc*8+j7)*WROW + lane];
        float4 wb = wlds[(cc*8+j7)*WROW + lane + 64];
        #pragma unroll
        for(int i=0;i<NL;i++){
          const float4 xv = *(const float4*)&xlds[mynb][cc][4*(lbase+i) + 4*j7];
          acc[i][0] = fmaf(xv.x, wa.x, fmaf(xv.y, wa.y, fmaf(xv.z, wa.z, fmaf(xv.w, wa.w, acc[i][0]))));
          acc[i][1] = fmaf(xv.x, wb.x, fmaf(xv.y, wb.y, fmaf(xv.z, wb.z, fmaf(xv.w, wb.w, acc[i][1]))));
        }
      }
    }
    __syncthreads();
  }
  int bsto = b0 + ((NB==1)?0:wq);
  int lsto = l0 + ((NB==1)? wq*NL : 0);
  float bA = bias[coA], bB = bias[coA+64];
  size_t baseA = (size_t)bsto*((size_t)COUT*LOUT) + (size_t)coA*LOUT + lsto;
  float4 o;
  o.x=fmaxf(acc[0][0]+bA,0.f); o.y=fmaxf(acc[1][0]+bA,0.f); o.z=fmaxf(acc[2][0]+bA,0.f); o.w=fmaxf(acc[3][0]+bA,0.f);
  *(float4*)&out[baseA] = o;
  o.x=fmaxf(acc[4][0]+bA,0.f); o.y=fmaxf(acc[5][0]+bA,0.f); o.z=fmaxf(acc[6][0]+bA,0.f); o.w=fmaxf(acc[7][0]+bA,0.f);
  *(float4*)&out[baseA+4] = o;
  size_t baseB = baseA + (size_t)64*LOUT;
  o.x=fmaxf(acc[0][1]+bB,0.f); o.y=fmaxf(acc[1][1]+bB,0.f); o.z=fmaxf(acc[2][1]+bB,0.f); o.w=fmaxf(acc[3][1]+bB,0.f);
  *(float4*)&out[baseB] = o;
  o.x=fmaxf(acc[4][1]+bB,0.f); o.y=fmaxf(acc[5][1]+bB,0.f); o.z=fmaxf(acc[6][1]+bB,0.f); o.w=fmaxf(acc[7][1]+bB,0.f);
  *(float4*)&out[baseB+4] = o;
}

// ---------------- projection: h_s / c_s = hflat @ {ph,pc}_w.T + b ----------------
__global__ __launch_bounds__(256) void proj_k(const float* __restrict__ act4,
    const float* __restrict__ phw, const float* __restrict__ phb,
    const float* __restrict__ pcw, const float* __restrict__ pcb,
    float* __restrict__ h0, float* __restrict__ cbuf){
  __shared__ __align__(16) float hl[8][512];
  int bid = blockIdx.x; int bt = bid & 15, rt = bid >> 4;
  int b0 = bt*8;
  int tid = threadIdx.x; int lane = tid & 63, wq = tid >> 6;
  int r = rt*64 + lane;                         // 0..1023 (h rows then c rows)
  const float* wrow = (r < 512) ? (phw + (size_t)r*8192) : (pcw + (size_t)(r-512)*8192);
  float acc0 = 0.f, acc1 = 0.f;
  int b_ = wq*2;
  for(int kc=0; kc<16; kc++){
    int k0 = kc*512;
    for(int idx=tid; idx<8*512; idx+=256){
      int bb = idx>>9; int kk = idx & 511;
      int kg = k0 + kk; int c = kg & 1023; int t = kg >> 10;
      hl[bb][kk] = act4[(size_t)(b0+bb)*8192 + c*8 + t];
    }
    __syncthreads();
    for(int k4=0;k4<128;k4++){
      float4 wv = *(const float4*)&wrow[k0 + 4*k4];
      float4 a = *(const float4*)&hl[b_][4*k4];
      float4 b4 = *(const float4*)&hl[b_+1][4*k4];
      acc0 = fmaf(wv.x,a.x,fmaf(wv.y,a.y,fmaf(wv.z,a.z,fmaf(wv.w,a.w,acc0))));
      acc1 = fmaf(wv.x,b4.x,fmaf(wv.y,b4.y,fmaf(wv.z,b4.z,fmaf(wv.w,b4.w,acc1))));
    }
    __syncthreads();
  }
  float bv = (r<512)? phb[r] : pcb[r-512];
  int ba = b0 + b_;
  if(r < 512){
    h0[(size_t)ba*512 + r] = acc0 + bv;
    h0[(size_t)(ba+1)*512 + r] = acc1 + bv;
  } else {
    cbuf[(size_t)ba*512 + (r-512)] = acc0 + bv;
    cbuf[(size_t)(ba+1)*512 + (r-512)] = acc1 + bv;
  }
}

// ---------------- one-time packs ----------------
__global__ __launch_bounds__(256) void pack_whh_k(const float* __restrict__ whh, float4* __restrict__ wp4){
  int idx = blockIdx.x*256 + threadIdx.x;       // 512*512
  if(idx >= 512*512) return;
  int u = idx & 511; int k = idx >> 9;
  float4 v;
  v.x = whh[(size_t)(u)*512 + k];
  v.y = whh[(size_t)(512+u)*512 + k];
  v.z = whh[(size_t)(1024+u)*512 + k];
  v.w = whh[(size_t)(1536+u)*512 + k];
  wp4[(size_t)k*512 + u] = v;
}

__global__ __launch_bounds__(256) void pack_e_k(const float* __restrict__ wih,
    const float* __restrict__ bih, const float* __restrict__ bhh,
    const float* __restrict__ embw, const float* __restrict__ embb,
    float* __restrict__ E0, float* __restrict__ E1, float* __restrict__ BX, float* __restrict__ B0){
  int idx = blockIdx.x*256 + threadIdx.x;       // 2048 rows
  if(idx >= 2048) return;
  int u = idx & 511, g = idx >> 9;
  int row = g*512 + u;
  const float* wr = wih + (size_t)row*512;
  float e0=0.f, e1=0.f, bx=0.f;
  for(int j=0;j<512;j++){
    float wv = wr[j];
    e0 = fmaf(wv, embw[j*2+0], e0);
    e1 = fmaf(wv, embw[j*2+1], e1);
    bx = fmaf(wv, embb[j], bx);
  }
  float b0v = bih[row] + bhh[row];
  E0[u*4+g] = e0; E1[u*4+g] = e1; BX[u*4+g] = bx + b0v; B0[u*4+g] = b0v;
}

// ---------------- LSTM step ----------------
// grid 256: bt=bid&7 (16 b), jt=bid>>3 (16 units). block 512: k-split halves.
__global__ __launch_bounds__(512) void lstm_step_k(
    const float* __restrict__ hprev, float* __restrict__ hnext, float* __restrict__ cbuf,
    const float4* __restrict__ wp4, const float4* __restrict__ E0v, const float4* __restrict__ E1v,
    const float4* __restrict__ BXv, const float4* __restrict__ B0v,
    const float* __restrict__ lf0w, const float* __restrict__ lf0b,
    const float* __restrict__ uvw, const float* __restrict__ uvb,
    float* __restrict__ dout, int t){
  __shared__ __align__(16) float hl[16][516];
  __shared__ __align__(16) float4 part4[2][16][16];
  __shared__ float red[16][32][2];
  __shared__ float lf_s[16], uv_s[16];
  int bid = blockIdx.x;
  int bt = bid & 7, jt = bid >> 3;
  int b0 = bt*16, j0 = jt*16;
  int tid = threadIdx.x;
  for(int idx=tid; idx<2048; idx+=512){
    int bb = idx >> 7, m = idx & 127;
    *(float4*)&hl[bb][m*4] = *(const float4*)&hprev[(size_t)(b0+bb)*512 + m*4];
  }
  __syncthreads();
  if(t > 0){
    int s = tid & 31, bb = tid >> 5;
    float p0=0.f, p1=0.f;
    int kbase = s*16;
    #pragma unroll
    for(int k=0;k<16;k++){
      float hv = hl[bb][kbase+k];
      p0 = fmaf(hv, lf0w[kbase+k], p0);
      p1 = fmaf(hv, uvw[kbase+k], p1);
    }
    red[bb][s][0]=p0; red[bb][s][1]=p1;
    __syncthreads();
    if(tid < 16){
      float a0=0.f, a1=0.f;
      for(int s2=0;s2<32;s2++){ a0+=red[tid][s2][0]; a1+=red[tid][s2][1]; }
      a0 += lf0b[0];
      a1 = sigm(a1 + uvb[0]);
      lf_s[tid]=a0; uv_s[tid]=a1;
      if(jt == 0){
        dout[(size_t)(b0+tid)*(2*NSTEPS) + (t-1)*2 + 0] = a0;
        dout[(size_t)(b0+tid)*(2*NSTEPS) + (t-1)*2 + 1] = a1;
      }
    }
    __syncthreads();
  }
  {
    int u = tid & 15, bb = (tid>>4) & 15, half = tid >> 8;
    int ug = j0 + u;
    float4 acc = {0.f,0.f,0.f,0.f};
    int k0 = half*256;
    #pragma unroll 4
    for(int k4=0;k4<64;k4++){
      int k = k0 + k4*4;
      float4 w0 = wp4[(size_t)(k+0)*512 + ug];
      float4 w1 = wp4[(size_t)(k+1)*512 + ug];
      float4 w2 = wp4[(size_t)(k+2)*512 + ug];
      float4 w3 = wp4[(size_t)(k+3)*512 + ug];
      float4 hv = *(const float4*)&hl[bb][k];
      acc.x = fmaf(hv.x,w0.x,acc.x); acc.y = fmaf(hv.x,w0.y,acc.y); acc.z = fmaf(hv.x,w0.z,acc.z); acc.w = fmaf(hv.x,w0.w,acc.w);
      acc.x = fmaf(hv.y,w1.x,acc.x); acc.y = fmaf(hv.y,w1.y,acc.y); acc.z = fmaf(hv.y,w1.z,acc.z); acc.w = fmaf(hv.y,w1.w,acc.w);
      acc.x = fmaf(hv.z,w2.x,acc.x); acc.y = fmaf(hv.z,w2.y,acc.y); acc.z = fmaf(hv.z,w2.z,acc.z); acc.w = fmaf(hv.z,w2.w,acc.w);
      acc.x = fmaf(hv.w,w3.x,acc.x); acc.y = fmaf(hv.w,w3.y,acc.y); acc.z = fmaf(hv.w,w3.z,acc.z); acc.w = fmaf(hv.w,w3.w,acc.w);
    }
    part4[half][bb][u] = acc;
  }
  __syncthreads();
  if(tid < 256){
    int u = tid & 15, bb = tid >> 4;
    int ug = j0 + u;
    float4 a = part4[0][bb][u], b4 = part4[1][bb][u];
    float gx = a.x + b4.x, gy = a.y + b4.y, gz = a.z + b4.z, gw = a.w + b4.w;
    float4 xp;
    if(t == 0){
      xp = B0v[ug];
    } else {
      float lf = lf_s[bb], uvv = uv_s[bb];
      float4 bx = BXv[ug], e0 = E0v[ug], e1 = E1v[ug];
      xp.x = fmaf(lf, e0.x, fmaf(uvv, e1.x, bx.x));
      xp.y = fmaf(lf, e0.y, fmaf(uvv, e1.y, bx.y));
      xp.z = fmaf(lf, e0.z, fmaf(uvv, e1.z, bx.z));
      xp.w = fmaf(lf, e0.w, fmaf(uvv, e1.w, bx.w));
    }
    float gi = sigm(gx + xp.x);
    float gf = sigm(gy + xp.y);
    float gg = tanhf(gz + xp.z);
    float go = sigm(gw + xp.w);
    size_t off = (size_t)(b0+bb)*512 + ug;
    float cn = fmaf(gf, cbuf[off], gi*gg);
    cbuf[off] = cn;
    hnext[off] = go * tanhf(cn);
  }
}

// ---------------- final output (t = 199) ----------------
__global__ __launch_bounds__(64) void final_k(const float* __restrict__ h,
    const float* __restrict__ lf0w, const float* __restrict__ lf0b,
    const float* __restrict__ uvw, const float* __restrict__ uvb,
    float* __restrict__ dout){
  int b = blockIdx.x; int lane = threadIdx.x;
  const float* hr = h + (size_t)b*512;
  float p0=0.f, p1=0.f;
  for(int k=lane;k<512;k+=64){
    float hv = hr[k];
    p0 = fmaf(hv, lf0w[k], p0);
    p1 = fmaf(hv, uvw[k], p1);
  }
  for(int off=32; off; off>>=1){
    p0 += __shfl_down(p0, off, 64);
    p1 += __shfl_down(p1, off, 64);
  }
  if(lane==0){
    dout[(size_t)b*(2*NSTEPS) + 199*2 + 0] = p0 + lf0b[0];
    dout[(size_t)b*(2*NSTEPS) + 199*2 + 1] = sigm(p1 + uvb[0]);
  }
}

extern "C" void kernel_launch(void* const* d_in, const int* in_sizes, int n_in,
                              void* d_out, int out_size, void* d_ws, size_t ws_size,
                              hipStream_t stream) {
  const float* x    = (const float*)d_in[0];
  const float* cw0  = (const float*)d_in[2];  const float* cb0 = (const float*)d_in[3];
  const float* cw1  = (const float*)d_in[4];  const float* cb1 = (const float*)d_in[5];
  const float* cw2  = (const float*)d_in[6];  const float* cb2 = (const float*)d_in[7];
  const float* cw3  = (const float*)d_in[8];  const float* cb3 = (const float*)d_in[9];
  const float* cw4  = (const float*)d_in[10]; const float* cb4 = (const float*)d_in[11];
  const float* phw  = (const float*)d_in[12]; const float* phb = (const float*)d_in[13];
  const float* pcw  = (const float*)d_in[14]; const float* pcb = (const float*)d_in[15];
  const float* wih  = (const float*)d_in[16]; const float* whh = (const float*)d_in[17];
  const float* bih  = (const float*)d_in[18]; const float* bhh = (const float*)d_in[19];
  const float* lf0w = (const float*)d_in[20]; const float* lf0b = (const float*)d_in[21];
  const float* uvw  = (const float*)d_in[22]; const float* uvb  = (const float*)d_in[23];
  const float* embw = (const float*)d_in[24]; const float* embb = (const float*)d_in[25];
  float* dout = (float*)d_out;

  float* ws = (float*)d_ws;
  float* actA = ws;                                // 16,777,216 floats (act0 / act2 / act4)
  float* actB = ws + 16777216;                     //  8,388,608 floats (act1 / act3)
  float4* wp4 = (float4*)(ws + 25165824);          //  1,048,576 floats
  float*  E0  = ws + 26214400;                     //  2048
  float*  E1  = E0 + 2048;
  float*  BX  = E1 + 2048;
  float*  B0  = BX + 2048;
  float*  h0  = B0 + 2048;                         // 65536
  float*  h1  = h0 + 65536;
  float*  cb  = h1 + 65536;                        // total ~26.4M floats (~106 MB)

  pack_whh_k<<<1024, 256, 0, stream>>>(whh, wp4);
  pack_e_k<<<8, 256, 0, stream>>>(wih, bih, bhh, embw, embb, E0, E1, BX, B0);

  conv0_k<<<65536, 256, 0, stream>>>(x, cw0, cb0, actA);
  convN_k< 64,2048,512,32,1, 128><<<2048, 256, 0, stream>>>(actA, cw1, cb1, actB);
  convN_k<128, 512,128,32,1, 256><<<1024, 256, 0, stream>>>(actB, cw2, cb2, actA);
  convN_k<256, 128, 32,32,1, 512><<< 512, 256, 0, stream>>>(actA, cw3, cb3, actB);
  convN_k<512,  32,  8, 8,4,1024><<< 256, 256, 0, stream>>>(actB, cw4, cb4, actA);

  proj_k<<<256, 256, 0, stream>>>(actA, phw, phb, pcw, pcb, h0, cb);

  for(int t=0; t<NSTEPS; t++){
    float* hp = (t & 1) ? h1 : h0;
    float* hn = (t & 1) ? h0 : h1;
    lstm_step_k<<<256, 512, 0, stream>>>(hp, hn, cb, wp4,
        (const float4*)E0, (const float4*)E1, (const float4*)BX, (const float4*)B0,
        lf0w, lf0b, uvw, uvb, dout, t);
  }
  final_k<<<128, 64, 0, stream>>>(h0, lf0w, lf0b, uvw, uvb, dout);
}

// Round 2
// 3826.160 us; speedup vs baseline: 2.5797x; 2.5797x over previous
//
#include <hip/hip_runtime.h>

#define NSTEPS 200

typedef __attribute__((ext_vector_type(8))) short bf16x8;
typedef __attribute__((ext_vector_type(4))) float f32x4;

__device__ __forceinline__ float sigm(float x){ return 1.0f/(1.0f + __expf(-x)); }

__device__ __forceinline__ unsigned short f2bf(float f){
  unsigned int u = __float_as_uint(f);
  u = u + 0x7FFFu + ((u>>16)&1u);
  return (unsigned short)(u>>16);
}
__device__ __forceinline__ float bf2f(unsigned short s){
  return __uint_as_float(((unsigned int)s)<<16);
}

__device__ __forceinline__ void gld_lds16(const void* g, void* l){
  __builtin_amdgcn_global_load_lds(
    (const __attribute__((address_space(1))) unsigned int*)g,
    (__attribute__((address_space(3))) unsigned int*)l, 16, 0, 0);
}

// ---------------- zero row pads of a padded bf16 activation buffer ----------------
__global__ __launch_bounds__(256) void zpad_k(unsigned short* __restrict__ p, int nrows, int L){
  int idx = blockIdx.x*256 + threadIdx.x;
  if(idx >= nrows*8) return;
  int row = idx>>3; int j = idx&7;
  int off = (j<4) ? j*4 : (16 + L + (j-4)*4);
  ushort4 z; z.x=0; z.y=0; z.z=0; z.w=0;
  *(ushort4*)&p[(size_t)row*(L+32) + off] = z;
}

// ---------------- pack conv weights: fp32 [CO][CI][31] -> bf16 [CO][CI*32] (slot0=0) ----------------
__global__ __launch_bounds__(256) void packw_k(const float* __restrict__ w, unsigned short* __restrict__ wpk, int total, int dummyCIN){
  int idx = blockIdx.x*256 + threadIdx.x;
  if(idx >= total) return;
  int k = idx & 31; int r = idx >> 5;   // r = co*CIN + ci
  wpk[idx] = (k >= 1) ? f2bf(w[(size_t)r*31 + (k-1)]) : (unsigned short)0;
}

// ---------------- conv0: Cin=1, Cout=64, L 8192->2048, fp32 VALU, bf16 padded out ----------------
__global__ __launch_bounds__(256) void conv0_k(const float* __restrict__ x,
    const float* __restrict__ w, const float* __restrict__ bias, unsigned short* __restrict__ act0){
  __shared__ float xl[1056];
  __shared__ float wl[64*31];
  __shared__ float bl[64];
  int b = blockIdx.x >> 3; int lt = blockIdx.x & 7;
  int l0 = lt*256; int tid = threadIdx.x;
  for(int i=tid;i<1056;i+=256){
    int g = 4*l0 - 15 + i;
    xl[i] = (g>=0 && g<8192) ? x[(size_t)b*8192 + g] : 0.f;
  }
  for(int i=tid;i<1984;i+=256) wl[i] = w[i];
  if(tid<64) bl[tid]=bias[tid];
  __syncthreads();
  float xr[31];
  #pragma unroll
  for(int j=0;j<31;j++) xr[j] = xl[4*tid + j];
  size_t obase = ((size_t)b*64)*2080 + 16 + l0 + tid;
  for(int co=0;co<64;co++){
    float acc = bl[co];
    #pragma unroll
    for(int j=0;j<31;j++) acc = fmaf(wl[co*31+j], xr[j], acc);
    act0[obase + (size_t)co*2080] = f2bf(fmaxf(acc,0.f));
  }
}

// ---------------- generic MFMA conv (as GEMM M=(b,l), N=co, K=ci*32+tap) ----------------
template<int CIN, int LIN, int LOUT, int LT, int NBT, int COUT, int KSPLIT>
__global__ __launch_bounds__(256,3) void conv_mfma_k(
    const unsigned short* __restrict__ actin,   // padded bf16 [B][CIN][LIN+32], data@+16
    const unsigned short* __restrict__ wpk,     // bf16 [COUT][CIN*32]
    const float* __restrict__ bias,
    unsigned short* __restrict__ actout,        // (KSPLIT==1) padded bf16 out
    float* __restrict__ partial)                // (KSPLIT>1) [KSPLIT][COUT][MT]
{
  constexpr int LINP  = LIN + 32;
  constexpr int LOUTP = LOUT + 32;
  constexpr int SPANB = 8*LT + 64;      // bytes per (ci, b') x-span
  constexpr int SC    = SPANB/16;
  constexpr int CA    = 2*NBT*SC;       // 16B chunks of A per K-step
  static_assert(CA <= 256, "CA");
  constexpr int ASZ   = CA*16;
  constexpr int BSZ   = 16384;          // 128 co x 128B
  constexpr int MT    = 128*LOUT;       // total M
  constexpr int MTILES= MT/128;
  constexpr int NT    = COUT/128;
  constexpr int NSTEP = CIN/2/KSPLIT;
  __shared__ __align__(16) char smem[2*(BSZ+ASZ)];
  char* Bb = smem;
  char* Ab = smem + 2*BSZ;

  int bid = blockIdx.x;
  int mt = bid % MTILES; bid /= MTILES;
  int nt = bid % NT;     int z = bid / NT;
  int b0 = (mt*128)/LOUT;
  int l0 = (mt*128)%LOUT;
  int cobase = nt*128;
  int s0 = z*NSTEP, s1 = s0 + NSTEP;

  int tid = threadIdx.x; int lane = tid&63; int wid = tid>>6;
  int wm = wid>>1, wn = wid&1;
  int l15 = lane&15, kg = lane>>4;

  // A staging descriptor (fixed per thread)
  int aq_c=0, aq_b=0, aq_j=0; bool a_act = tid < CA;
  { int q = tid; aq_c = q/(NBT*SC); int r = q%(NBT*SC); aq_b = r/SC; aq_j = r%SC; }

  auto STAGE = [&](int st){
    int buf = st&1;
    #pragma unroll
    for(int i=0;i<4;i++){
      int qb = tid + i*256;
      int col = qb>>3; int j = qb&7;
      const char* src = (const char*)wpk + (size_t)(cobase+col)*(CIN*64) + (size_t)st*128
                        + ((j*16) ^ ((col&7)<<4));
      gld_lds16(src, Bb + buf*BSZ + qb*16);
    }
    if(a_act){
      int ci = 2*st + aq_c;
      const char* src = (const char*)actin
          + 2*((size_t)((b0+aq_b)*CIN + ci)*LINP + 4*l0) + aq_j*16;
      gld_lds16(src, Ab + buf*ASZ + tid*16);
    }
  };

  // per-lane read offsets
  int abyte[2][4], bbyte[2][4];
  #pragma unroll
  for(int c=0;c<2;c++){
    #pragma unroll
    for(int mf=0;mf<4;mf++){
      int r = wm*64 + mf*16 + l15;
      int bp = (NBT>1) ? (r/LT) : 0;
      int ll = (NBT>1) ? (r%LT) : r;
      abyte[c][mf] = (c*NBT + bp)*SPANB + 8*ll + 16*kg;
    }
    #pragma unroll
    for(int nf=0;nf<4;nf++){
      int col = wn*64 + nf*16 + l15;
      bbyte[c][nf] = col*128 + ((c*64 + 16*kg) ^ ((col&7)<<4));
    }
  }

  const f32x4 vz = {0.f,0.f,0.f,0.f};
  f32x4 acc[4][4];
  #pragma unroll
  for(int i=0;i<4;i++)
    #pragma unroll
    for(int j=0;j<4;j++) acc[i][j] = vz;

  STAGE(s0);
  __syncthreads();
  for(int s=s0;s<s1;s++){
    if(s+1<s1) STAGE(s+1);
    const char* Ac = Ab + (s&1)*ASZ;
    const char* Bc = Bb + (s&1)*BSZ;
    #pragma unroll
    for(int c=0;c<2;c++){
      bf16x8 af[4], bfv[4];
      #pragma unroll
      for(int mf=0;mf<4;mf++){
        const char* ap = Ac + abyte[c][mf];
        union { unsigned long long u[2]; bf16x8 v; } t;
        t.u[0] = *(const unsigned long long*)ap;
        t.u[1] = *(const unsigned long long*)(ap+8);
        af[mf] = t.v;
      }
      #pragma unroll
      for(int nf=0;nf<4;nf++) bfv[nf] = *(const bf16x8*)(Bc + bbyte[c][nf]);
      #pragma unroll
      for(int mf=0;mf<4;mf++)
        #pragma unroll
        for(int nf=0;nf<4;nf++)
          acc[mf][nf] = __builtin_amdgcn_mfma_f32_16x16x32_bf16(af[mf], bfv[nf], acc[mf][nf], 0,0,0);
    }
    __syncthreads();
  }

  if constexpr (KSPLIT == 1){
    #pragma unroll
    for(int nf=0;nf<4;nf++){
      int co = cobase + wn*64 + nf*16 + l15;
      float bv = bias[co];
      #pragma unroll
      for(int mf=0;mf<4;mf++){
        int m = wm*64 + mf*16 + 4*kg;
        int bp = (NBT>1) ? (m/LT) : 0;
        int ll = (NBT>1) ? (m%LT) : m;
        f32x4 a = acc[mf][nf];
        ushort4 o;
        o.x = f2bf(fmaxf(a[0]+bv,0.f));
        o.y = f2bf(fmaxf(a[1]+bv,0.f));
        o.z = f2bf(fmaxf(a[2]+bv,0.f));
        o.w = f2bf(fmaxf(a[3]+bv,0.f));
        size_t off = ((size_t)((b0+bp)*COUT + co))*LOUTP + 16 + l0 + ll;
        *(ushort4*)&actout[off] = o;
      }
    }
  } else {
    #pragma unroll
    for(int nf=0;nf<4;nf++){
      int co = cobase + wn*64 + nf*16 + l15;
      #pragma unroll
      for(int mf=0;mf<4;mf++){
        int mloc = wm*64 + mf*16 + 4*kg;
        int mglob = mt*128 + mloc;
        *(f32x4*)&partial[((size_t)(z*COUT + co))*MT + mglob] = acc[mf][nf];
      }
    }
  }
}

// ---------------- reduce K-split partials -> bf16 padded act ----------------
template<int COUT, int MT, int LOUT, int KS>
__global__ __launch_bounds__(256) void reduce_k(const float* __restrict__ partial,
    const float* __restrict__ bias, unsigned short* __restrict__ actout){
  int idx = blockIdx.x*256 + threadIdx.x;
  if(idx >= COUT*(MT/4)) return;
  int m4 = idx % (MT/4); int co = idx / (MT/4);
  int m = m4*4;
  float4 a = *(const float4*)&partial[(size_t)co*MT + m];
  #pragma unroll
  for(int zz=1; zz<KS; zz++){
    float4 b = *(const float4*)&partial[((size_t)(zz*COUT + co))*MT + m];
    a.x += b.x; a.y += b.y; a.z += b.z; a.w += b.w;
  }
  float bv = bias[co];
  int b_ = m / LOUT, l = m % LOUT;
  ushort4 o;
  o.x = f2bf(fmaxf(a.x+bv,0.f));
  o.y = f2bf(fmaxf(a.y+bv,0.f));
  o.z = f2bf(fmaxf(a.z+bv,0.f));
  o.w = f2bf(fmaxf(a.w+bv,0.f));
  *(ushort4*)&actout[((size_t)(b_*COUT + co))*(LOUT+32) + 16 + l] = o;
}

// ---------------- projection: h_s / c_s = hflat @ {ph,pc}_w.T + b (fp32) ----------------
__global__ __launch_bounds__(256) void proj_k(const unsigned short* __restrict__ act4,
    const float* __restrict__ phw, const float* __restrict__ phb,
    const float* __restrict__ pcw, const float* __restrict__ pcb,
    float* __restrict__ h0, float* __restrict__ cbuf){
  __shared__ __align__(16) float hl[8][512];
  int bid = blockIdx.x; int bt = bid & 15, rt = bid >> 4;
  int b0 = bt*8;
  int tid = threadIdx.x; int lane = tid & 63, wq = tid >> 6;
  int r = rt*64 + lane;
  const float* wrow = (r < 512) ? (phw + (size_t)r*8192) : (pcw + (size_t)(r-512)*8192);
  float acc0 = 0.f, acc1 = 0.f;
  int b_ = wq*2;
  for(int kc=0; kc<16; kc++){
    int k0 = kc*512;
    for(int idx=tid; idx<8*512; idx+=256){
      int bb = idx>>9; int kk = idx & 511;
      int kg = k0 + kk; int c = kg & 1023; int tq = kg >> 10;
      hl[bb][kk] = bf2f(act4[((size_t)(b0+bb)*1024 + c)*40 + 16 + tq]);
    }
    __syncthreads();
    for(int k4=0;k4<128;k4++){
      float4 wv = *(const float4*)&wrow[k0 + 4*k4];
      float4 a = *(const float4*)&hl[b_][4*k4];
      float4 b4 = *(const float4*)&hl[b_+1][4*k4];
      acc0 = fmaf(wv.x,a.x,fmaf(wv.y,a.y,fmaf(wv.z,a.z,fmaf(wv.w,a.w,acc0))));
      acc1 = fmaf(wv.x,b4.x,fmaf(wv.y,b4.y,fmaf(wv.z,b4.z,fmaf(wv.w,b4.w,acc1))));
    }
    __syncthreads();
  }
  float bv = (r<512)? phb[r] : pcb[r-512];
  int ba = b0 + b_;
  if(r < 512){
    h0[(size_t)ba*512 + r] = acc0 + bv;
    h0[(size_t)(ba+1)*512 + r] = acc1 + bv;
  } else {
    cbuf[(size_t)ba*512 + (r-512)] = acc0 + bv;
    cbuf[(size_t)(ba+1)*512 + (r-512)] = acc1 + bv;
  }
}

// ---------------- one-time packs for LSTM ----------------
__global__ __launch_bounds__(256) void pack_whh_k(const float* __restrict__ whh, float4* __restrict__ wp4){
  int idx = blockIdx.x*256 + threadIdx.x;
  if(idx >= 512*512) return;
  int u = idx & 511; int k = idx >> 9;
  float4 v;
  v.x = whh[(size_t)(u)*512 + k];
  v.y = whh[(size_t)(512+u)*512 + k];
  v.z = whh[(size_t)(1024+u)*512 + k];
  v.w = whh[(size_t)(1536+u)*512 + k];
  wp4[(size_t)k*512 + u] = v;
}

__global__ __launch_bounds__(256) void pack_e_k(const float* __restrict__ wih,
    const float* __restrict__ bih, const float* __restrict__ bhh,
    const float* __restrict__ embw, const float* __restrict__ embb,
    float* __restrict__ E0, float* __restrict__ E1, float* __restrict__ BX, float* __restrict__ B0){
  int idx = blockIdx.x*256 + threadIdx.x;
  if(idx >= 2048) return;
  int u = idx & 511, g = idx >> 9;
  int row = g*512 + u;
  const float* wr = wih + (size_t)row*512;
  float e0=0.f, e1=0.f, bx=0.f;
  for(int j=0;j<512;j++){
    float wv = wr[j];
    e0 = fmaf(wv, embw[j*2+0], e0);
    e1 = fmaf(wv, embw[j*2+1], e1);
    bx = fmaf(wv, embb[j], bx);
  }
  float b0v = bih[row] + bhh[row];
  E0[u*4+g] = e0; E1[u*4+g] = e1; BX[u*4+g] = bx + b0v; B0[u*4+g] = b0v;
}

// ---------------- LSTM step v2: LDS-staged weights, 256 blocks ----------------
__global__ __launch_bounds__(256) void lstm2_k(
    const float* __restrict__ hprev, float* __restrict__ hnext, float* __restrict__ cbuf,
    const float4* __restrict__ wp4, const float4* __restrict__ E0v, const float4* __restrict__ E1v,
    const float4* __restrict__ BXv, const float4* __restrict__ B0v,
    const float* __restrict__ lf0w, const float* __restrict__ lf0b,
    const float* __restrict__ uvw, const float* __restrict__ uvb,
    float* __restrict__ dout, int t){
  __shared__ __align__(16) float hl[8][520];
  __shared__ __align__(16) float4 wl[2][64][32];
  __shared__ float lf_s[8], uv_s[8];
  int bid = blockIdx.x; int ut = bid & 15; int bt = bid >> 4;
  int j0 = ut*32; int b0 = bt*8;
  int tid = threadIdx.x; int u = tid>>3; int bg = tid&7;

  auto STAGEW = [&](int c){
    #pragma unroll
    for(int i=0;i<8;i++){
      int idx = i*256 + tid;
      int k = idx>>5, ul = idx&31;
      gld_lds16((const void*)(wp4 + ((size_t)(c*64+k)*512 + j0 + ul)),
                (void*)&wl[c&1][k][ul]);
    }
  };

  #pragma unroll
  for(int i=0;i<4;i++){
    int idx = i*256 + tid; int bb = idx>>7; int kk = (idx&127)*4;
    *(float4*)&hl[bb][kk] = *(const float4*)&hprev[(size_t)(b0+bb)*512 + kk];
  }
  STAGEW(0);
  __syncthreads();

  if(t > 0){
    int hb = tid>>5; int s = tid&31;
    float p0=0.f, p1=0.f;
    #pragma unroll
    for(int k=0;k<16;k++){
      float hv = hl[hb][s*16+k];
      p0 = fmaf(hv, lf0w[s*16+k], p0);
      p1 = fmaf(hv, uvw[s*16+k], p1);
    }
    for(int off=16; off; off>>=1){
      p0 += __shfl_down(p0, off, 32);
      p1 += __shfl_down(p1, off, 32);
    }
    if(s==0){
      p0 += lf0b[0];
      p1 = sigm(p1 + uvb[0]);
      lf_s[hb]=p0; uv_s[hb]=p1;
      if(ut==0){
        dout[(size_t)(b0+hb)*(2*NSTEPS) + (t-1)*2 + 0] = p0;
        dout[(size_t)(b0+hb)*(2*NSTEPS) + (t-1)*2 + 1] = p1;
      }
    }
  }

  float4 acc; acc.x=0.f; acc.y=0.f; acc.z=0.f; acc.w=0.f;
  for(int kc=0;kc<8;kc++){
    if(kc<7) STAGEW(kc+1);
    const float4 (*wc)[32] = wl[kc&1];
    #pragma unroll
    for(int k4=0;k4<16;k4++){
      float4 hv = *(const float4*)&hl[bg][kc*64 + k4*4];
      float4 w0 = wc[k4*4+0][u];
      float4 w1 = wc[k4*4+1][u];
      float4 w2 = wc[k4*4+2][u];
      float4 w3 = wc[k4*4+3][u];
      acc.x = fmaf(hv.x,w0.x,acc.x); acc.y = fmaf(hv.x,w0.y,acc.y); acc.z = fmaf(hv.x,w0.z,acc.z); acc.w = fmaf(hv.x,w0.w,acc.w);
      acc.x = fmaf(hv.y,w1.x,acc.x); acc.y = fmaf(hv.y,w1.y,acc.y); acc.z = fmaf(hv.y,w1.z,acc.z); acc.w = fmaf(hv.y,w1.w,acc.w);
      acc.x = fmaf(hv.z,w2.x,acc.x); acc.y = fmaf(hv.z,w2.y,acc.y); acc.z = fmaf(hv.z,w2.z,acc.z); acc.w = fmaf(hv.z,w2.w,acc.w);
      acc.x = fmaf(hv.w,w3.x,acc.x); acc.y = fmaf(hv.w,w3.y,acc.y); acc.z = fmaf(hv.w,w3.z,acc.z); acc.w = fmaf(hv.w,w3.w,acc.w);
    }
    __syncthreads();
  }

  int ug = j0 + u;
  float4 xp;
  if(t == 0){
    xp = make_float4(B0v[ug].x, B0v[ug].y, B0v[ug].z, B0v[ug].w);
  } else {
    float lf = lf_s[bg], uvv = uv_s[bg];
    float4 bx = BXv[ug], e0 = E0v[ug], e1 = E1v[ug];
    xp.x = fmaf(lf, e0.x, fmaf(uvv, e1.x, bx.x));
    xp.y = fmaf(lf, e0.y, fmaf(uvv, e1.y, bx.y));
    xp.z = fmaf(lf, e0.z, fmaf(uvv, e1.z, bx.z));
    xp.w = fmaf(lf, e0.w, fmaf(uvv, e1.w, bx.w));
  }
  float gi = sigm(acc.x + xp.x);
  float gf = sigm(acc.y + xp.y);
  float gg = tanhf(acc.z + xp.z);
  float go = sigm(acc.w + xp.w);
  size_t off = (size_t)(b0+bg)*512 + ug;
  float cn = fmaf(gf, cbuf[off], gi*gg);
  cbuf[off] = cn;
  hnext[off] = go * tanhf(cn);
}

// ---------------- final output (t = 199) ----------------
__global__ __launch_bounds__(64) void final_k(const float* __restrict__ h,
    const float* __restrict__ lf0w, const float* __restrict__ lf0b,
    const float* __restrict__ uvw, const float* __restrict__ uvb,
    float* __restrict__ dout){
  int b = blockIdx.x; int lane = threadIdx.x;
  const float* hr = h + (size_t)b*512;
  float p0=0.f, p1=0.f;
  for(int k=lane;k<512;k+=64){
    float hv = hr[k];
    p0 = fmaf(hv, lf0w[k], p0);
    p1 = fmaf(hv, uvw[k], p1);
  }
  for(int off=32; off; off>>=1){
    p0 += __shfl_down(p0, off, 64);
    p1 += __shfl_down(p1, off, 64);
  }
  if(lane==0){
    dout[(size_t)b*(2*NSTEPS) + 199*2 + 0] = p0 + lf0b[0];
    dout[(size_t)b*(2*NSTEPS) + 199*2 + 1] = sigm(p1 + uvb[0]);
  }
}

extern "C" void kernel_launch(void* const* d_in, const int* in_sizes, int n_in,
                              void* d_out, int out_size, void* d_ws, size_t ws_size,
                              hipStream_t stream) {
  const float* x    = (const float*)d_in[0];
  const float* cw0  = (const float*)d_in[2];  const float* cb0 = (const float*)d_in[3];
  const float* cw1  = (const float*)d_in[4];  const float* cb1 = (const float*)d_in[5];
  const float* cw2  = (const float*)d_in[6];  const float* cb2 = (const float*)d_in[7];
  const float* cw3  = (const float*)d_in[8];  const float* cb3 = (const float*)d_in[9];
  const float* cw4  = (const float*)d_in[10]; const float* cb4 = (const float*)d_in[11];
  const float* phw  = (const float*)d_in[12]; const float* phb = (const float*)d_in[13];
  const float* pcw  = (const float*)d_in[14]; const float* pcb = (const float*)d_in[15];
  const float* wih  = (const float*)d_in[16]; const float* whh = (const float*)d_in[17];
  const float* bih  = (const float*)d_in[18]; const float* bhh = (const float*)d_in[19];
  const float* lf0w = (const float*)d_in[20]; const float* lf0b = (const float*)d_in[21];
  const float* uvw  = (const float*)d_in[22]; const float* uvb  = (const float*)d_in[23];
  const float* embw = (const float*)d_in[24]; const float* embb = (const float*)d_in[25];
  float* dout = (float*)d_out;

  float* ws = (float*)d_ws;
  // region A (34,078,720 B = 8,519,680 floats): act0 / act2 / act4 / partial
  unsigned short* act0 = (unsigned short*)ws;
  unsigned short* act2 = (unsigned short*)ws;
  unsigned short* act4 = (unsigned short*)ws;
  float*          part = ws + 2883584;            // A + 11 MB (16 MB partials)
  // region B (17,825,792 B): act1 / act3
  unsigned short* act1 = (unsigned short*)(ws + 8519680);
  unsigned short* act3 = (unsigned short*)(ws + 8519680);
  // packed conv weights (bf16)
  unsigned short* wpk1 = (unsigned short*)(ws + 12976128);
  unsigned short* wpk2 = wpk1 + 262144;
  unsigned short* wpk3 = wpk2 + 1048576;
  unsigned short* wpk4 = wpk3 + 4194304;
  // LSTM
  float4* wp4 = (float4*)(ws + 24117248);
  float*  E0  = ws + 25165824;
  float*  E1  = E0 + 2048;
  float*  BX  = E1 + 2048;
  float*  B0  = BX + 2048;
  float*  h0  = B0 + 2048;
  float*  h1  = h0 + 65536;
  float*  cb  = h1 + 65536;

  // ---- packs & pads (independent) ----
  packw_k<<<(128*64*32+255)/256, 256, 0, stream>>>(cw1, wpk1, 128*64*32, 64);
  packw_k<<<(256*128*32+255)/256, 256, 0, stream>>>(cw2, wpk2, 256*128*32, 128);
  packw_k<<<(512*256*32+255)/256, 256, 0, stream>>>(cw3, wpk3, 512*256*32, 256);
  packw_k<<<(1024*512*32+255)/256, 256, 0, stream>>>(cw4, wpk4, 1024*512*32, 512);
  pack_whh_k<<<1024, 256, 0, stream>>>(whh, wp4);
  pack_e_k<<<8, 256, 0, stream>>>(wih, bih, bhh, embw, embb, E0, E1, BX, B0);
  zpad_k<<<(128*64*8+255)/256, 256, 0, stream>>>(act0, 128*64, 2048);
  zpad_k<<<(128*128*8+255)/256, 256, 0, stream>>>(act1, 128*128, 512);

  // ---- conv stack ----
  conv0_k<<<1024, 256, 0, stream>>>(x, cw0, cb0, act0);
  conv_mfma_k<64,2048,512,128,1,128,1><<<512, 256, 0, stream>>>(act0, wpk1, cb1, act1, nullptr);
  zpad_k<<<(128*256*8+255)/256, 256, 0, stream>>>(act2, 128*256, 128);   // act0 dead
  conv_mfma_k<128,512,128,128,1,256,1><<<256, 256, 0, stream>>>(act1, wpk2, cb2, act2, nullptr);
  zpad_k<<<(128*512*8+255)/256, 256, 0, stream>>>(act3, 128*512, 32);    // act1 dead
  conv_mfma_k<256,128,32,32,4,512,2><<<256, 256, 0, stream>>>(act2, wpk3, cb3, nullptr, part);
  reduce_k<512,4096,32,2><<<2048, 256, 0, stream>>>(part, cb3, act3);
  conv_mfma_k<512,32,8,8,16,1024,4><<<256, 256, 0, stream>>>(act3, wpk4, cb4, nullptr, part);
  reduce_k<1024,1024,8,4><<<1024, 256, 0, stream>>>(part, cb4, act4);

  // ---- projection ----
  proj_k<<<256, 256, 0, stream>>>(act4, phw, phb, pcw, pcb, h0, cb);

  // ---- LSTM ----
  for(int t=0; t<NSTEPS; t++){
    float* hp = (t & 1) ? h1 : h0;
    float* hn = (t & 1) ? h0 : h1;
    lstm2_k<<<256, 256, 0, stream>>>(hp, hn, cb, wp4,
        (const float4*)E0, (const float4*)E1, (const float4*)BX, (const float4*)B0,
        lf0w, lf0b, uvw, uvb, dout, t);
  }
  final_k<<<128, 64, 0, stream>>>(h0, lf0w, lf0b, uvw, uvb, dout);
}

// Round 3
// 1582.153 us; speedup vs baseline: 6.2385x; 2.4183x over previous
//
#include <hip/hip_runtime.h>

#define NSTEPS 200

typedef __attribute__((ext_vector_type(8))) short bf16x8;
typedef __attribute__((ext_vector_type(4))) float f32x4;

__device__ __forceinline__ float sigm(float x){ return 1.0f/(1.0f + __expf(-x)); }

__device__ __forceinline__ unsigned short f2bf(float f){
  unsigned int u = __float_as_uint(f);
  u = u + 0x7FFFu + ((u>>16)&1u);
  return (unsigned short)(u>>16);
}
__device__ __forceinline__ float bf2f(unsigned short s){
  return __uint_as_float(((unsigned int)s)<<16);
}

__device__ __forceinline__ void gld_lds16(const void* g, void* l){
  __builtin_amdgcn_global_load_lds(
    (const __attribute__((address_space(1))) unsigned int*)g,
    (__attribute__((address_space(3))) unsigned int*)l, 16, 0, 0);
}

// ---------------- zero row pads of a padded bf16 activation buffer ----------------
__global__ __launch_bounds__(256) void zpad_k(unsigned short* __restrict__ p, int nrows, int L){
  int idx = blockIdx.x*256 + threadIdx.x;
  if(idx >= nrows*8) return;
  int row = idx>>3; int j = idx&7;
  int off = (j<4) ? j*4 : (16 + L + (j-4)*4);
  ushort4 z; z.x=0; z.y=0; z.z=0; z.w=0;
  *(ushort4*)&p[(size_t)row*(L+32) + off] = z;
}

// ---------------- pack conv weights: fp32 [CO][CI][31] -> bf16 [CO][CI*32] (slot0=0) ----------------
__global__ __launch_bounds__(256) void packw_k(const float* __restrict__ w, unsigned short* __restrict__ wpk, int total){
  int idx = blockIdx.x*256 + threadIdx.x;
  if(idx >= total) return;
  int k = idx & 31; int r = idx >> 5;
  wpk[idx] = (k >= 1) ? f2bf(w[(size_t)r*31 + (k-1)]) : (unsigned short)0;
}

// ---------------- conv0: Cin=1, Cout=64, L 8192->2048, fp32 VALU, bf16 padded out ----------------
__global__ __launch_bounds__(256) void conv0_k(const float* __restrict__ x,
    const float* __restrict__ w, const float* __restrict__ bias, unsigned short* __restrict__ act0){
  __shared__ float xl[1056];
  __shared__ float wl[64*31];
  __shared__ float bl[64];
  int b = blockIdx.x >> 3; int lt = blockIdx.x & 7;
  int l0 = lt*256; int tid = threadIdx.x;
  for(int i=tid;i<1056;i+=256){
    int g = 4*l0 - 15 + i;
    xl[i] = (g>=0 && g<8192) ? x[(size_t)b*8192 + g] : 0.f;
  }
  for(int i=tid;i<1984;i+=256) wl[i] = w[i];
  if(tid<64) bl[tid]=bias[tid];
  __syncthreads();
  float xr[31];
  #pragma unroll
  for(int j=0;j<31;j++) xr[j] = xl[4*tid + j];
  size_t obase = ((size_t)b*64)*2080 + 16 + l0 + tid;
  for(int co=0;co<64;co++){
    float acc = bl[co];
    #pragma unroll
    for(int j=0;j<31;j++) acc = fmaf(wl[co*31+j], xr[j], acc);
    act0[obase + (size_t)co*2080] = f2bf(fmaxf(acc,0.f));
  }
}

// ---------------- generic MFMA conv (as GEMM M=(b,l), N=co, K=ci*32+tap) ----------------
template<int CIN, int LIN, int LOUT, int LT, int NBT, int COUT, int KSPLIT>
__global__ __launch_bounds__(256,3) void conv_mfma_k(
    const unsigned short* __restrict__ actin,
    const unsigned short* __restrict__ wpk,
    const float* __restrict__ bias,
    unsigned short* __restrict__ actout,
    float* __restrict__ partial)
{
  constexpr int LINP  = LIN + 32;
  constexpr int LOUTP = LOUT + 32;
  constexpr int SPANB = 8*LT + 64;
  constexpr int SC    = SPANB/16;
  constexpr int CA    = 2*NBT*SC;
  static_assert(CA <= 256, "CA");
  constexpr int ASZ   = CA*16;
  constexpr int BSZ   = 16384;
  constexpr int MT    = 128*LOUT;
  constexpr int MTILES= MT/128;
  constexpr int NT    = COUT/128;
  constexpr int NSTEP = CIN/2/KSPLIT;
  __shared__ __align__(16) char smem[2*(BSZ+ASZ)];
  char* Bb = smem;
  char* Ab = smem + 2*BSZ;

  int bid = blockIdx.x;
  int mt = bid % MTILES; bid /= MTILES;
  int nt = bid % NT;     int z = bid / NT;
  int b0 = (mt*128)/LOUT;
  int l0 = (mt*128)%LOUT;
  int cobase = nt*128;
  int s0 = z*NSTEP, s1 = s0 + NSTEP;

  int tid = threadIdx.x; int lane = tid&63; int wid = tid>>6;
  int wm = wid>>1, wn = wid&1;
  int l15 = lane&15, kg = lane>>4;

  int aq_c=0, aq_b=0, aq_j=0; bool a_act = tid < CA;
  { int q = tid; aq_c = q/(NBT*SC); int r = q%(NBT*SC); aq_b = r/SC; aq_j = r%SC; }

  auto STAGE = [&](int st){
    int buf = st&1;
    #pragma unroll
    for(int i=0;i<4;i++){
      int qb = tid + i*256;
      int col = qb>>3; int j = qb&7;
      const char* src = (const char*)wpk + (size_t)(cobase+col)*(CIN*64) + (size_t)st*128
                        + ((j*16) ^ ((col&7)<<4));
      gld_lds16(src, Bb + buf*BSZ + qb*16);
    }
    if(a_act){
      int ci = 2*st + aq_c;
      const char* src = (const char*)actin
          + 2*((size_t)((b0+aq_b)*CIN + ci)*LINP + 4*l0) + aq_j*16;
      gld_lds16(src, Ab + buf*ASZ + tid*16);
    }
  };

  int abyte[2][4], bbyte[2][4];
  #pragma unroll
  for(int c=0;c<2;c++){
    #pragma unroll
    for(int mf=0;mf<4;mf++){
      int r = wm*64 + mf*16 + l15;
      int bp = (NBT>1) ? (r/LT) : 0;
      int ll = (NBT>1) ? (r%LT) : r;
      abyte[c][mf] = (c*NBT + bp)*SPANB + 8*ll + 16*kg;
    }
    #pragma unroll
    for(int nf=0;nf<4;nf++){
      int col = wn*64 + nf*16 + l15;
      bbyte[c][nf] = col*128 + ((c*64 + 16*kg) ^ ((col&7)<<4));
    }
  }

  const f32x4 vz = {0.f,0.f,0.f,0.f};
  f32x4 acc[4][4];
  #pragma unroll
  for(int i=0;i<4;i++)
    #pragma unroll
    for(int j=0;j<4;j++) acc[i][j] = vz;

  STAGE(s0);
  __syncthreads();
  for(int s=s0;s<s1;s++){
    if(s+1<s1) STAGE(s+1);
    const char* Ac = Ab + (s&1)*ASZ;
    const char* Bc = Bb + (s&1)*BSZ;
    #pragma unroll
    for(int c=0;c<2;c++){
      bf16x8 af[4], bfv[4];
      #pragma unroll
      for(int mf=0;mf<4;mf++){
        const char* ap = Ac + abyte[c][mf];
        union { unsigned long long u[2]; bf16x8 v; } t;
        t.u[0] = *(const unsigned long long*)ap;
        t.u[1] = *(const unsigned long long*)(ap+8);
        af[mf] = t.v;
      }
      #pragma unroll
      for(int nf=0;nf<4;nf++) bfv[nf] = *(const bf16x8*)(Bc + bbyte[c][nf]);
      #pragma unroll
      for(int mf=0;mf<4;mf++)
        #pragma unroll
        for(int nf=0;nf<4;nf++)
          acc[mf][nf] = __builtin_amdgcn_mfma_f32_16x16x32_bf16(af[mf], bfv[nf], acc[mf][nf], 0,0,0);
    }
    __syncthreads();
  }

  if constexpr (KSPLIT == 1){
    #pragma unroll
    for(int nf=0;nf<4;nf++){
      int co = cobase + wn*64 + nf*16 + l15;
      float bv = bias[co];
      #pragma unroll
      for(int mf=0;mf<4;mf++){
        int m = wm*64 + mf*16 + 4*kg;
        int bp = (NBT>1) ? (m/LT) : 0;
        int ll = (NBT>1) ? (m%LT) : m;
        f32x4 a = acc[mf][nf];
        ushort4 o;
        o.x = f2bf(fmaxf(a[0]+bv,0.f));
        o.y = f2bf(fmaxf(a[1]+bv,0.f));
        o.z = f2bf(fmaxf(a[2]+bv,0.f));
        o.w = f2bf(fmaxf(a[3]+bv,0.f));
        size_t off = ((size_t)((b0+bp)*COUT + co))*LOUTP + 16 + l0 + ll;
        *(ushort4*)&actout[off] = o;
      }
    }
  } else {
    #pragma unroll
    for(int nf=0;nf<4;nf++){
      int co = cobase + wn*64 + nf*16 + l15;
      #pragma unroll
      for(int mf=0;mf<4;mf++){
        int mloc = wm*64 + mf*16 + 4*kg;
        int mglob = mt*128 + mloc;
        *(f32x4*)&partial[((size_t)(z*COUT + co))*MT + mglob] = acc[mf][nf];
      }
    }
  }
}

// ---------------- reduce K-split partials -> bf16 padded act ----------------
template<int COUT, int MT, int LOUT, int KS>
__global__ __launch_bounds__(256) void reduce_k(const float* __restrict__ partial,
    const float* __restrict__ bias, unsigned short* __restrict__ actout){
  int idx = blockIdx.x*256 + threadIdx.x;
  if(idx >= COUT*(MT/4)) return;
  int m4 = idx % (MT/4); int co = idx / (MT/4);
  int m = m4*4;
  float4 a = *(const float4*)&partial[(size_t)co*MT + m];
  #pragma unroll
  for(int zz=1; zz<KS; zz++){
    float4 b = *(const float4*)&partial[((size_t)(zz*COUT + co))*MT + m];
    a.x += b.x; a.y += b.y; a.z += b.z; a.w += b.w;
  }
  float bv = bias[co];
  int b_ = m / LOUT, l = m % LOUT;
  ushort4 o;
  o.x = f2bf(fmaxf(a.x+bv,0.f));
  o.y = f2bf(fmaxf(a.y+bv,0.f));
  o.z = f2bf(fmaxf(a.z+bv,0.f));
  o.w = f2bf(fmaxf(a.w+bv,0.f));
  *(ushort4*)&actout[((size_t)(b_*COUT + co))*(LOUT+32) + 16 + l] = o;
}

// ---------------- gather act4 -> hflatb bf16 [B][8192], pre-swizzled by batch ----------------
// hflat[b][d], d = l*1024 + c = act4[b][c][l]; stored at element d ^ ((b&7)<<3)
__global__ __launch_bounds__(256) void gather_k(const unsigned short* __restrict__ act4,
    unsigned short* __restrict__ hflatb){
  __shared__ unsigned short trans[8][260];
  int b = blockIdx.x >> 2, ct = blockIdx.x & 3;
  int c0 = ct*256;
  int tid = threadIdx.x;
  uint4 v = *(const uint4*)&act4[((size_t)(b*1024 + c0 + tid))*40 + 16];
  unsigned short* pv = (unsigned short*)&v;
  #pragma unroll
  for(int l=0;l<8;l++) trans[l][tid] = pv[l];
  __syncthreads();
  int l = tid>>5, cg = tid&31;
  uint4 o;
  unsigned short* po = (unsigned short*)&o;
  #pragma unroll
  for(int e=0;e<8;e++) po[e] = trans[l][cg*8+e];
  int G = l*128 + ct*32 + cg;
  *(uint4*)&hflatb[(size_t)b*8192 + (size_t)((G ^ (b&7))*8)] = o;
}

// ---------------- pack proj weights: [1024 n][8192 d] bf16 (n<512: ph_w, else pc_w) ----------------
__global__ __launch_bounds__(256) void packwproj_k(const float* __restrict__ phw,
    const float* __restrict__ pcw, unsigned short* __restrict__ wproj){
  int idx = blockIdx.x*256 + threadIdx.x;
  if(idx >= 1024*8192) return;
  int n = idx >> 13, d = idx & 8191;
  float v = (n < 512) ? phw[(size_t)n*8192 + d] : pcw[(size_t)(n-512)*8192 + d];
  wproj[idx] = f2bf(v);
}

// ---------------- pack LSTM weights: [2048 n][512 k] bf16, n = u*4+g ----------------
__global__ __launch_bounds__(256) void packwlstm_k(const float* __restrict__ whh,
    unsigned short* __restrict__ wpb){
  int idx = blockIdx.x*256 + threadIdx.x;
  if(idx >= 2048*512) return;
  int n = idx >> 9, k = idx & 511;
  int u = n >> 2, g = n & 3;
  wpb[idx] = f2bf(whh[(size_t)(g*512+u)*512 + k]);
}

__global__ __launch_bounds__(256) void pack_e_k(const float* __restrict__ wih,
    const float* __restrict__ bih, const float* __restrict__ bhh,
    const float* __restrict__ embw, const float* __restrict__ embb,
    float* __restrict__ E0, float* __restrict__ E1, float* __restrict__ BX, float* __restrict__ B0){
  int idx = blockIdx.x*256 + threadIdx.x;
  if(idx >= 2048) return;
  int u = idx & 511, g = idx >> 9;
  int row = g*512 + u;
  const float* wr = wih + (size_t)row*512;
  float e0=0.f, e1=0.f, bx=0.f;
  for(int j=0;j<512;j++){
    float wv = wr[j];
    e0 = fmaf(wv, embw[j*2+0], e0);
    e1 = fmaf(wv, embw[j*2+1], e1);
    bx = fmaf(wv, embb[j], bx);
  }
  float b0v = bih[row] + bhh[row];
  E0[u*4+g] = e0; E1[u*4+g] = e1; BX[u*4+g] = bx + b0v; B0[u*4+g] = b0v;
}

// ---------------- projection via MFMA: [128 b x 8192 d] @ [8192 d x 1024 n] ----------------
__global__ __launch_bounds__(256) void projm_k(
    const unsigned short* __restrict__ hflatb,
    const unsigned short* __restrict__ wproj,
    const float* __restrict__ phb, const float* __restrict__ pcb,
    unsigned short* __restrict__ hbf0, float* __restrict__ cbuf)
{
  __shared__ __align__(16) char Bb[2*16384];
  __shared__ __align__(16) char Ab[2*4096];
  int bid = blockIdx.x;
  int bt = bid & 3, nt = bid >> 2;
  int b0 = bt*32, n0 = nt*128;
  int tid = threadIdx.x, lane = tid&63, wn = tid>>6;
  int l15 = lane&15, kg = lane>>4;

  auto STAGE = [&](int kc){
    #pragma unroll
    for(int i=0;i<4;i++){
      int qb = tid + i*256;
      int col = qb>>3, j = qb&7;
      const char* src = (const char*)wproj + (size_t)(n0+col)*16384 + (size_t)kc*128
                        + ((j*16) ^ ((col&7)<<4));
      gld_lds16(src, Bb + (kc&1)*16384 + qb*16);
    }
    { int row = tid>>3, j = tid&7;
      const char* src = (const char*)hflatb + (size_t)(b0+row)*16384 + (size_t)kc*128 + j*16;
      gld_lds16(src, Ab + (kc&1)*4096 + tid*16); }
  };

  const f32x4 vz = {0.f,0.f,0.f,0.f};
  f32x4 acc[2][2];
  acc[0][0]=vz; acc[0][1]=vz; acc[1][0]=vz; acc[1][1]=vz;

  STAGE(0);
  __syncthreads();
  for(int kc=0;kc<128;kc++){
    if(kc<127) STAGE(kc+1);
    const char* Bc = Bb + (kc&1)*16384;
    const char* Ac = Ab + (kc&1)*4096;
    #pragma unroll
    for(int ks=0;ks<2;ks++){
      bf16x8 af[2], bfv[2];
      #pragma unroll
      for(int mf=0;mf<2;mf++){
        int row = mf*16 + l15;
        af[mf] = *(const bf16x8*)(Ac + row*128 + ((ks*64+kg*16) ^ ((row&7)<<4)));
      }
      #pragma unroll
      for(int nf=0;nf<2;nf++){
        int col = wn*32 + nf*16 + l15;
        bfv[nf] = *(const bf16x8*)(Bc + col*128 + ((ks*64+kg*16) ^ ((col&7)<<4)));
      }
      #pragma unroll
      for(int mf=0;mf<2;mf++)
        #pragma unroll
        for(int nf=0;nf<2;nf++)
          acc[mf][nf] = __builtin_amdgcn_mfma_f32_16x16x32_bf16(af[mf], bfv[nf], acc[mf][nf], 0,0,0);
    }
    __syncthreads();
  }
  #pragma unroll
  for(int mf=0;mf<2;mf++){
    #pragma unroll
    for(int nf=0;nf<2;nf++){
      int n = n0 + wn*32 + nf*16 + l15;
      #pragma unroll
      for(int j=0;j<4;j++){
        int b = b0 + mf*16 + kg*4 + j;
        float v = acc[mf][nf][j];
        if(n < 512){
          hbf0[(size_t)b*512 + (n ^ ((b&7)<<3))] = f2bf(v + phb[n]);
        } else {
          cbuf[(size_t)b*512 + (n-512)] = v + pcb[n-512];
        }
      }
    }
  }
}

// ---------------- LSTM step v3: MFMA gates, bf16 h, 128 blocks ----------------
__global__ __launch_bounds__(256) void lstm3_k(
    const unsigned short* __restrict__ hbfprev,
    unsigned short* __restrict__ hbfnext,
    float* __restrict__ cbuf,
    const unsigned short* __restrict__ wpb,
    const float4* __restrict__ E0v, const float4* __restrict__ E1v,
    const float4* __restrict__ BXv, const float4* __restrict__ B0v,
    const float* __restrict__ lf0w, const float* __restrict__ lf0b,
    const float* __restrict__ uvw, const float* __restrict__ uvb,
    float* __restrict__ dout, int t)
{
  __shared__ __align__(16) char Bb[2*16384];
  __shared__ __align__(16) char Ab[16384];
  __shared__ __align__(16) float gates[16][136];
  __shared__ float red0[16][17], red1[16][17];
  __shared__ float lf_s[16], uv_s[16];

  int bid = blockIdx.x;
  int bt = bid & 7, ut = bid >> 3;
  int b0 = bt*16, n0 = ut*128;
  int tid = threadIdx.x, lane = tid&63, wn = tid>>6;
  int l15 = lane&15, kg = lane>>4;

  auto STAGEB = [&](int kc){
    #pragma unroll
    for(int i=0;i<4;i++){
      int qb = tid + i*256;
      int col = qb>>3, j = qb&7;
      const char* src = (const char*)wpb + (size_t)(n0+col)*1024 + kc*128
                        + ((j*16) ^ ((col&7)<<4));
      gld_lds16(src, Bb + (kc&1)*16384 + qb*16);
    }
  };

  #pragma unroll
  for(int i=0;i<4;i++){
    int qb = tid + i*256;
    gld_lds16((const char*)hbfprev + (size_t)b0*1024 + (size_t)qb*16, Ab + qb*16);
  }
  STAGEB(0);
  __syncthreads();

  const f32x4 vz = {0.f,0.f,0.f,0.f};
  f32x4 acc0 = vz, acc1 = vz;
  for(int kc=0;kc<8;kc++){
    if(kc<7) STAGEB(kc+1);
    const char* Bc = Bb + (kc&1)*16384;
    #pragma unroll
    for(int ks=0;ks<2;ks++){
      int kb = kc*128 + ks*64 + kg*16;
      bf16x8 af = *(const bf16x8*)(Ab + l15*1024 + (kb ^ ((l15&7)<<4)));
      int c0 = wn*32 + l15;
      bf16x8 b0f = *(const bf16x8*)(Bc + c0*128 + ((ks*64 + kg*16) ^ ((c0&7)<<4)));
      int c1 = c0 + 16;
      bf16x8 b1f = *(const bf16x8*)(Bc + c1*128 + ((ks*64 + kg*16) ^ ((c1&7)<<4)));
      acc0 = __builtin_amdgcn_mfma_f32_16x16x32_bf16(af, b0f, acc0, 0,0,0);
      acc1 = __builtin_amdgcn_mfma_f32_16x16x32_bf16(af, b1f, acc1, 0,0,0);
    }
    __syncthreads();
  }

  #pragma unroll
  for(int j=0;j<4;j++){
    gates[kg*4+j][wn*32 + l15]      = acc0[j];
    gates[kg*4+j][wn*32 + 16 + l15] = acc1[j];
  }
  int hb = tid & 15, hs = tid >> 4;
  if(t > 0){
    float p0 = 0.f, p1 = 0.f;
    #pragma unroll
    for(int j=0;j<4;j++){
      bf16x8 hv = *(const bf16x8*)(Ab + hb*1024 + ((hs*64 + j*16) ^ ((hb&7)<<4)));
      #pragma unroll
      for(int e=0;e<8;e++){
        float h = bf2f((unsigned short)hv[e]);
        int k = hs*32 + j*8 + e;
        p0 = fmaf(h, lf0w[k], p0);
        p1 = fmaf(h, uvw[k], p1);
      }
    }
    red0[hs][hb] = p0; red1[hs][hb] = p1;
  }
  __syncthreads();
  if(t > 0 && tid < 16){
    float a0=0.f, a1=0.f;
    #pragma unroll
    for(int s2=0;s2<16;s2++){ a0 += red0[s2][tid]; a1 += red1[s2][tid]; }
    a0 += lf0b[0];
    a1 = sigm(a1 + uvb[0]);
    lf_s[tid] = a0; uv_s[tid] = a1;
    if(ut == 0){
      dout[(size_t)(b0+tid)*(2*NSTEPS) + (t-1)*2 + 0] = a0;
      dout[(size_t)(b0+tid)*(2*NSTEPS) + (t-1)*2 + 1] = a1;
    }
  }
  __syncthreads();
  #pragma unroll
  for(int p=0;p<2;p++){
    int bu = tid + p*256;
    int b = bu & 15, ul = bu >> 4;
    int u_g = ut*32 + ul;
    float4 g4 = *(const float4*)&gates[b][ul*4];
    float4 xp;
    if(t == 0){
      xp = B0v[u_g];
    } else {
      float lf = lf_s[b], uvv = uv_s[b];
      float4 e0 = E0v[u_g], e1 = E1v[u_g], bx = BXv[u_g];
      xp.x = fmaf(lf, e0.x, fmaf(uvv, e1.x, bx.x));
      xp.y = fmaf(lf, e0.y, fmaf(uvv, e1.y, bx.y));
      xp.z = fmaf(lf, e0.z, fmaf(uvv, e1.z, bx.z));
      xp.w = fmaf(lf, e0.w, fmaf(uvv, e1.w, bx.w));
    }
    float gi = sigm(g4.x + xp.x);
    float gf = sigm(g4.y + xp.y);
    float gg = tanhf(g4.z + xp.z);
    float go = sigm(g4.w + xp.w);
    size_t off = (size_t)(b0+b)*512 + u_g;
    float cn = fmaf(gf, cbuf[off], gi*gg);
    cbuf[off] = cn;
    float hn = go * tanhf(cn);
    hbfnext[(size_t)(b0+b)*512 + (u_g ^ ((b&7)<<3))] = f2bf(hn);
  }
}

// ---------------- final output (t = 199) from bf16 h ----------------
__global__ __launch_bounds__(64) void final_k(const unsigned short* __restrict__ hbf,
    const float* __restrict__ lf0w, const float* __restrict__ lf0b,
    const float* __restrict__ uvw, const float* __restrict__ uvb,
    float* __restrict__ dout){
  int b = blockIdx.x; int lane = threadIdx.x;
  float p0=0.f, p1=0.f;
  for(int k=lane;k<512;k+=64){
    float hv = bf2f(hbf[(size_t)b*512 + (k ^ ((b&7)<<3))]);
    p0 = fmaf(hv, lf0w[k], p0);
    p1 = fmaf(hv, uvw[k], p1);
  }
  for(int off=32; off; off>>=1){
    p0 += __shfl_down(p0, off, 64);
    p1 += __shfl_down(p1, off, 64);
  }
  if(lane==0){
    dout[(size_t)b*(2*NSTEPS) + 199*2 + 0] = p0 + lf0b[0];
    dout[(size_t)b*(2*NSTEPS) + 199*2 + 1] = sigm(p1 + uvb[0]);
  }
}

extern "C" void kernel_launch(void* const* d_in, const int* in_sizes, int n_in,
                              void* d_out, int out_size, void* d_ws, size_t ws_size,
                              hipStream_t stream) {
  const float* x    = (const float*)d_in[0];
  const float* cw0  = (const float*)d_in[2];  const float* cb0 = (const float*)d_in[3];
  const float* cw1  = (const float*)d_in[4];  const float* cb1 = (const float*)d_in[5];
  const float* cw2  = (const float*)d_in[6];  const float* cb2 = (const float*)d_in[7];
  const float* cw3  = (const float*)d_in[8];  const float* cb3 = (const float*)d_in[9];
  const float* cw4  = (const float*)d_in[10]; const float* cb4 = (const float*)d_in[11];
  const float* phw  = (const float*)d_in[12]; const float* phb = (const float*)d_in[13];
  const float* pcw  = (const float*)d_in[14]; const float* pcb = (const float*)d_in[15];
  const float* wih  = (const float*)d_in[16]; const float* whh = (const float*)d_in[17];
  const float* bih  = (const float*)d_in[18]; const float* bhh = (const float*)d_in[19];
  const float* lf0w = (const float*)d_in[20]; const float* lf0b = (const float*)d_in[21];
  const float* uvw  = (const float*)d_in[22]; const float* uvb  = (const float*)d_in[23];
  const float* embw = (const float*)d_in[24]; const float* embb = (const float*)d_in[25];
  float* dout = (float*)d_out;

  float* ws = (float*)d_ws;
  // region A: act0/act2/act4 at ws+0; partials / wproj / hflatb after act regions
  unsigned short* act0 = (unsigned short*)ws;       // 17,039,360 ush (34 MB)
  unsigned short* act2 = (unsigned short*)ws;       // 10.5 MB
  unsigned short* act4 = (unsigned short*)ws;       // 10.5 MB
  float*          part = ws + 2883584;              // 16 MB partials (during convs)
  unsigned short* wproj= (unsigned short*)(ws + 2883584);   // 16.7 MB (after convs)
  unsigned short* hflatb=(unsigned short*)(ws + 7077888);   // 2 MB
  // region B: act1/act3
  unsigned short* act1 = (unsigned short*)(ws + 8519680);
  unsigned short* act3 = (unsigned short*)(ws + 8519680);
  // packed conv weights (bf16)
  unsigned short* wpk1 = (unsigned short*)(ws + 12976128);
  unsigned short* wpk2 = wpk1 + 262144;
  unsigned short* wpk3 = wpk2 + 1048576;
  unsigned short* wpk4 = wpk3 + 4194304;
  // LSTM
  unsigned short* wpb = (unsigned short*)(ws + 24117248);   // 2 MB
  float*  E0  = ws + 24641536;
  float*  E1  = E0 + 2048;
  float*  BX  = E1 + 2048;
  float*  B0  = BX + 2048;
  float*  cb  = ws + 24649728;                      // 65536 fl
  unsigned short* hbf0 = (unsigned short*)(ws + 24715264);  // 65536 ush
  unsigned short* hbf1 = (unsigned short*)(ws + 24748032);

  // ---- packs & pads ----
  packw_k<<<(128*64*32+255)/256, 256, 0, stream>>>(cw1, wpk1, 128*64*32);
  packw_k<<<(256*128*32+255)/256, 256, 0, stream>>>(cw2, wpk2, 256*128*32);
  packw_k<<<(512*256*32+255)/256, 256, 0, stream>>>(cw3, wpk3, 512*256*32);
  packw_k<<<(1024*512*32+255)/256, 256, 0, stream>>>(cw4, wpk4, 1024*512*32);
  packwlstm_k<<<4096, 256, 0, stream>>>(whh, wpb);
  pack_e_k<<<8, 256, 0, stream>>>(wih, bih, bhh, embw, embb, E0, E1, BX, B0);
  zpad_k<<<(128*64*8+255)/256, 256, 0, stream>>>(act0, 128*64, 2048);
  zpad_k<<<(128*128*8+255)/256, 256, 0, stream>>>(act1, 128*128, 512);

  // ---- conv stack ----
  conv0_k<<<1024, 256, 0, stream>>>(x, cw0, cb0, act0);
  conv_mfma_k<64,2048,512,128,1,128,1><<<512, 256, 0, stream>>>(act0, wpk1, cb1, act1, nullptr);
  zpad_k<<<(128*256*8+255)/256, 256, 0, stream>>>(act2, 128*256, 128);
  conv_mfma_k<128,512,128,128,1,256,1><<<256, 256, 0, stream>>>(act1, wpk2, cb2, act2, nullptr);
  zpad_k<<<(128*512*8+255)/256, 256, 0, stream>>>(act3, 128*512, 32);
  conv_mfma_k<256,128,32,32,4,512,2><<<256, 256, 0, stream>>>(act2, wpk3, cb3, nullptr, part);
  reduce_k<512,4096,32,2><<<2048, 256, 0, stream>>>(part, cb3, act3);
  conv_mfma_k<512,32,8,8,16,1024,4><<<256, 256, 0, stream>>>(act3, wpk4, cb4, nullptr, part);
  reduce_k<1024,1024,8,4><<<1024, 256, 0, stream>>>(part, cb4, act4);

  // ---- proj (MFMA) ----
  packwproj_k<<<32768, 256, 0, stream>>>(phw, pcw, wproj);
  gather_k<<<512, 256, 0, stream>>>(act4, hflatb);
  projm_k<<<32, 256, 0, stream>>>(hflatb, wproj, phb, pcb, hbf0, cb);

  // ---- LSTM ----
  for(int t=0; t<NSTEPS; t++){
    unsigned short* hp = (t & 1) ? hbf1 : hbf0;
    unsigned short* hn = (t & 1) ? hbf0 : hbf1;
    lstm3_k<<<128, 256, 0, stream>>>(hp, hn, cb, wpb,
        (const float4*)E0, (const float4*)E1, (const float4*)BX, (const float4*)B0,
        lf0w, lf0b, uvw, uvb, dout, t);
  }
  final_k<<<128, 64, 0, stream>>>(hbf0, lf0w, lf0b, uvw, uvb, dout);
}